// Round 1
// baseline (5137.648 us; speedup 1.0000x reference)
//
#include <hip/hip_runtime.h>
#include <hip/hip_bf16.h>
#include <math.h>

// Problem constants (B=1)
#define S_LEN 2048
#define HDIM  4096
#define NQ_H  32
#define NKV_H 8
#define HD_   128
// Derived
#define DQ (NQ_H*HD_)   // 4096
#define DKV (NKV_H*HD_) // 1024

// ---------------------------------------------------------------------------
// fp32 GEMM: C[M,N] = A[M,K] @ B[K,N], all row-major. M%128==0, N%128==0, K%16==0.
// 128x128 tile, 256 threads, 8x8 micro-tile split as 2x(4 rows) x 2x(4 cols)
// at +64 offsets so LDS reads are conflict-free and C-writes coalesce.
// ---------------------------------------------------------------------------
__global__ __launch_bounds__(256) void gemm_f32(const float* __restrict__ A,
                                                const float* __restrict__ B,
                                                float* __restrict__ C,
                                                int M, int N, int K) {
    __shared__ float As[16][128 + 4];  // stored transposed: As[k][m]
    __shared__ float Bs[16][128 + 4];  // Bs[k][n]

    const int t  = threadIdx.x;
    const int tx = t & 15;      // 0..15 (col group)
    const int ty = t >> 4;      // 0..15 (row group)... only 0..15; rows use ty&3? no:
    // micro mapping: rows = m0 + {ty4+i, 64+ty4+i}, cols = n0 + {tx*4+j, 64+tx*4+j}
    const int ty4 = (t >> 4) & 3;        // 0..3  -> but we need 16 row groups...
    // NOTE: we need 16x16 thread grid: tx in 0..15 cols, tyy in 0..15 rows.
    const int tyy = t >> 4;              // 0..15
    const int m0 = blockIdx.y * 128;
    const int n0 = blockIdx.x * 128;
    (void)ty4; (void)ty;

    // row base within tile for this thread: first 4 rows at tyy*4 is wrong (needs 64 rows)
    // Correct mapping: rows { (tyy&7)*8? } -- keep it simple & proven:
    // rows: r0 = (tyy)*4 for tyy in 0..15 covers 0..63; second half +64.
    const int rbase = tyy * 4;           // 0..60
    const int cbase = tx * 4;            // 0..60

    float acc[8][8];
#pragma unroll
    for (int i = 0; i < 8; ++i)
#pragma unroll
        for (int j = 0; j < 8; ++j) acc[i][j] = 0.f;

    for (int k0 = 0; k0 < K; k0 += 16) {
#pragma unroll
        for (int l = 0; l < 2; ++l) {
            int idx = t + l * 256;              // 0..511
            // A tile: 128 rows x 16 k -> As[k][m]
            int ar = idx >> 2;                  // 0..127
            int ak = (idx & 3) << 2;            // 0,4,8,12
            float4 av = *(const float4*)&A[(size_t)(m0 + ar) * K + k0 + ak];
            As[ak + 0][ar] = av.x;
            As[ak + 1][ar] = av.y;
            As[ak + 2][ar] = av.z;
            As[ak + 3][ar] = av.w;
            // B tile: 16 k x 128 n -> Bs[k][n]
            int bk = idx >> 5;                  // 0..15
            int bc = (idx & 31) << 2;           // 0..124
            *(float4*)&Bs[bk][bc] = *(const float4*)&B[(size_t)(k0 + bk) * N + n0 + bc];
        }
        __syncthreads();

#pragma unroll
        for (int kk = 0; kk < 16; ++kk) {
            float a[8], b[8];
            *(float4*)&a[0] = *(const float4*)&As[kk][rbase];
            *(float4*)&a[4] = *(const float4*)&As[kk][rbase + 64];
            *(float4*)&b[0] = *(const float4*)&Bs[kk][cbase];
            *(float4*)&b[4] = *(const float4*)&Bs[kk][cbase + 64];
#pragma unroll
            for (int i = 0; i < 8; ++i)
#pragma unroll
                for (int j = 0; j < 8; ++j)
                    acc[i][j] += a[i] * b[j];
        }
        __syncthreads();
    }

    // write back
#pragma unroll
    for (int i = 0; i < 8; ++i) {
        int m = m0 + ((i < 4) ? (rbase + i) : (64 + rbase + i - 4));
#pragma unroll
        for (int jh = 0; jh < 2; ++jh) {
            int n = n0 + ((jh == 0) ? cbase : (64 + cbase));
            float4 cv;
            cv.x = acc[i][jh * 4 + 0];
            cv.y = acc[i][jh * 4 + 1];
            cv.z = acc[i][jh * 4 + 2];
            cv.w = acc[i][jh * 4 + 3];
            *(float4*)&C[(size_t)m * N + n] = cv;
        }
    }
}

// ---------------------------------------------------------------------------
// RoPE in place: x is (S, nh*128). out[d] = x[d]*cos - x[d+64]*sin;
// out[d+64] = x[d+64]*cos + x[d]*sin   (cos[d]==cos[d+64], sin likewise)
// ---------------------------------------------------------------------------
__global__ void rope_kernel(float* __restrict__ x, const float* __restrict__ cosT,
                            const float* __restrict__ sinT, int nh) {
    int idx = blockIdx.x * blockDim.x + threadIdx.x;
    int total = S_LEN * nh * 64;
    if (idx >= total) return;
    int d = idx & 63;
    int h = (idx >> 6) % nh;
    int s = idx / (nh * 64);
    float c  = cosT[s * HD_ + d];
    float sn = sinT[s * HD_ + d];
    float* p = x + (size_t)s * nh * HD_ + h * HD_ + d;
    float x1 = p[0];
    float x2 = p[64];
    p[0]  = x1 * c - x2 * sn;
    p[64] = x2 * c + x1 * sn;
}

// ---------------------------------------------------------------------------
// Causal GQA flash attention, fp32.
// Q: (S, 4096) rope'd; K,V: (S, 1024); O: (S, 4096).
// Block: 256 threads = 64 query rows x 4 lanes; lane `sub` owns interleaved
// d-slice {sub*4 + 16*i4 + e}. Q row in registers; K/V staged in shared
// (same buffer, serialized by barriers); raw scores via LDS; online softmax.
// ---------------------------------------------------------------------------
__global__ __launch_bounds__(256) void attn_kernel(const float* __restrict__ Q,
                                                   const float* __restrict__ K,
                                                   const float* __restrict__ V,
                                                   float* __restrict__ O) {
    constexpr int BQ = 64, BK = 64;
    __shared__ float KVs[BK][HD_ + 4];
    __shared__ float Ps[BQ][BK + 1];

    const int qt  = blockIdx.x;       // query tile
    const int h   = blockIdx.y;       // q head
    const int kvh = h >> 2;           // kv head (groups = 4)
    const int q0  = qt * BQ;
    const int t   = threadIdx.x;
    const int row = t >> 2;           // 0..63
    const int sub = t & 3;            // 0..3
    const int qrow = q0 + row;

    const float scale = 0.08838834764831845f;  // 1/sqrt(128)

    // load this row's q slice into registers (interleaved float4 slices)
    float qv[32];
    const float* qp = Q + (size_t)qrow * DQ + h * HD_;
#pragma unroll
    for (int i4 = 0; i4 < 8; ++i4)
        *(float4*)&qv[i4 * 4] = *(const float4*)&qp[sub * 4 + i4 * 16];

    float m = -INFINITY, l = 0.f;
    float o[32];
#pragma unroll
    for (int i = 0; i < 32; ++i) o[i] = 0.f;

    for (int kt = 0; kt <= qt; ++kt) {
        const int k0 = kt * BK;
        __syncthreads();  // protect KVs against previous iteration's PV reads
        // stage K tile: 64 x 128
#pragma unroll
        for (int l2 = 0; l2 < 8; ++l2) {
            int idx = t + l2 * 256;       // 0..2047
            int r = idx >> 5;             // 0..63
            int c = (idx & 31) << 2;      // 0..124
            *(float4*)&KVs[r][c] = *(const float4*)&K[(size_t)(k0 + r) * DKV + kvh * HD_ + c];
        }
        __syncthreads();

        // scores for all 64 keys (each lane: partial over its 32 dims, then
        // butterfly over the 4 lanes of the row)
        float tmax = -INFINITY;
        for (int j = 0; j < BK; ++j) {
            float p = 0.f;
#pragma unroll
            for (int i4 = 0; i4 < 8; ++i4) {
                float4 kv = *(const float4*)&KVs[j][sub * 4 + i4 * 16];
                p += qv[i4 * 4 + 0] * kv.x + qv[i4 * 4 + 1] * kv.y +
                     qv[i4 * 4 + 2] * kv.z + qv[i4 * 4 + 3] * kv.w;
            }
            p += __shfl_xor(p, 1);
            p += __shfl_xor(p, 2);
            p *= scale;
            if (k0 + j > qrow) p = -INFINITY;  // causal mask
            if (sub == (j & 3)) Ps[row][j] = p;
            tmax = fmaxf(tmax, p);
        }

        const float mnew  = fmaxf(m, tmax);
        const float alpha = __expf(m - mnew);  // exp(-inf)=0 on first tile
        l *= alpha;
#pragma unroll
        for (int i = 0; i < 32; ++i) o[i] *= alpha;
        m = mnew;

        __syncthreads();  // scores done reading K
        // stage V tile into the same buffer
#pragma unroll
        for (int l2 = 0; l2 < 8; ++l2) {
            int idx = t + l2 * 256;
            int r = idx >> 5;
            int c = (idx & 31) << 2;
            *(float4*)&KVs[r][c] = *(const float4*)&V[(size_t)(k0 + r) * DKV + kvh * HD_ + c];
        }
        __syncthreads();

        // PV accumulate
        for (int j = 0; j < BK; ++j) {
            float p = __expf(Ps[row][j] - mnew);  // masked -> exp(-inf)=0
            l += p;
#pragma unroll
            for (int i4 = 0; i4 < 8; ++i4) {
                float4 vv = *(const float4*)&KVs[j][sub * 4 + i4 * 16];
                o[i4 * 4 + 0] += p * vv.x;
                o[i4 * 4 + 1] += p * vv.y;
                o[i4 * 4 + 2] += p * vv.z;
                o[i4 * 4 + 3] += p * vv.w;
            }
        }
    }

    // epilogue: normalize and store
    const float inv = 1.f / l;
    float* op = O + (size_t)qrow * DQ + h * HD_;
#pragma unroll
    for (int i4 = 0; i4 < 8; ++i4) {
        float4 ov;
        ov.x = o[i4 * 4 + 0] * inv;
        ov.y = o[i4 * 4 + 1] * inv;
        ov.z = o[i4 * 4 + 2] * inv;
        ov.w = o[i4 * 4 + 3] * inv;
        *(float4*)&op[sub * 4 + i4 * 16] = ov;
    }
}

// ---------------------------------------------------------------------------
extern "C" void kernel_launch(void* const* d_in, const int* in_sizes, int n_in,
                              void* d_out, int out_size, void* d_ws, size_t ws_size,
                              hipStream_t stream) {
    const float* X    = (const float*)d_in[0];  // (1, 2048, 4096)
    const float* cosT = (const float*)d_in[1];  // (2048, 128)
    const float* sinT = (const float*)d_in[2];  // (2048, 128)
    const float* wq   = (const float*)d_in[3];  // (4096, 4096)
    const float* wk   = (const float*)d_in[4];  // (4096, 1024)
    const float* wv   = (const float*)d_in[5];  // (4096, 1024)
    const float* wo   = (const float*)d_in[6];  // (4096, 4096)
    float* out = (float*)d_out;                 // (1, 2048, 4096)

    // workspace layout (floats): q 8M | k 2M | v 2M | ao 8M  => 80 MB
    float* q  = (float*)d_ws;
    float* k  = q + (size_t)S_LEN * DQ;
    float* v  = k + (size_t)S_LEN * DKV;
    float* ao = v + (size_t)S_LEN * DKV;

    dim3 blk(256);

    // projections
    gemm_f32<<<dim3(DQ / 128, S_LEN / 128), blk, 0, stream>>>(X, wq, q, S_LEN, DQ, HDIM);
    gemm_f32<<<dim3(DKV / 128, S_LEN / 128), blk, 0, stream>>>(X, wk, k, S_LEN, DKV, HDIM);
    gemm_f32<<<dim3(DKV / 128, S_LEN / 128), blk, 0, stream>>>(X, wv, v, S_LEN, DKV, HDIM);

    // rope (q then k)
    rope_kernel<<<(S_LEN * NQ_H * 64) / 256, 256, 0, stream>>>(q, cosT, sinT, NQ_H);
    rope_kernel<<<(S_LEN * NKV_H * 64) / 256, 256, 0, stream>>>(k, cosT, sinT, NKV_H);

    // attention
    attn_kernel<<<dim3(S_LEN / 64, NQ_H), blk, 0, stream>>>(q, k, v, ao);

    // output projection
    gemm_f32<<<dim3(HDIM / 128, S_LEN / 128), blk, 0, stream>>>(ao, wo, out, S_LEN, HDIM, DQ);
}

// Round 3
// 809.021 us; speedup vs baseline: 6.3504x; 6.3504x over previous
//
#include <hip/hip_runtime.h>
#include <hip/hip_bf16.h>
#include <math.h>

// Problem constants (B=1)
#define S_LEN 2048
#define HDIM  4096
#define NQ_H  32
#define NKV_H 8
#define HD_   128
#define DQ (NQ_H*HD_)   // 4096
#define DKV (NKV_H*HD_) // 1024

typedef unsigned short u16;
typedef unsigned int   u32;
typedef __attribute__((ext_vector_type(8))) short short8;   // 8 bf16 = 4 VGPRs
typedef __attribute__((ext_vector_type(4))) float f32x4;

__device__ __forceinline__ u16 bf16_rne(float x) {
    u32 u = __float_as_uint(x);
    u = (u + 0x7FFFu + ((u >> 16) & 1u)) >> 16;
    return (u16)u;
}
__device__ __forceinline__ float bf16_to_f(u16 h) {
    return __uint_as_float(((u32)h) << 16);
}
__device__ __forceinline__ void glds16(const u16* g, u16* l) {
    __builtin_amdgcn_global_load_lds(
        (const __attribute__((address_space(1))) u32*)g,
        (__attribute__((address_space(3))) u32*)l,
        16, 0, 0);
}

// ---------------------------------------------------------------------------
// fp32 -> bf16 row-major convert. n % 2048 == 0.
// ---------------------------------------------------------------------------
__global__ __launch_bounds__(256) void cvt_bf16(const float* __restrict__ in,
                                                u16* __restrict__ out, int n) {
    int i = (blockIdx.x * 256 + threadIdx.x) * 8;
    if (i >= n) return;
    float4 a = *(const float4*)&in[i];
    float4 b = *(const float4*)&in[i + 4];
    u16 h[8];
    h[0] = bf16_rne(a.x); h[1] = bf16_rne(a.y); h[2] = bf16_rne(a.z); h[3] = bf16_rne(a.w);
    h[4] = bf16_rne(b.x); h[5] = bf16_rne(b.y); h[6] = bf16_rne(b.z); h[7] = bf16_rne(b.w);
    *(uint4*)&out[i] = *(uint4*)h;
}

// ---------------------------------------------------------------------------
// W (K x N fp32, row-major) -> W^T bf16 (N x K).  K,N % 32 == 0.
// ---------------------------------------------------------------------------
__global__ __launch_bounds__(256) void cvtT(const float* __restrict__ W,
                                            u16* __restrict__ WT, int K, int N) {
    __shared__ float tile[32][33];
    const int n0 = blockIdx.x * 32;
    const int k0 = blockIdx.y * 32;
    const int tx = threadIdx.x & 31;
    const int ty = threadIdx.x >> 5;   // 0..7
#pragma unroll
    for (int i = 0; i < 4; ++i)
        tile[ty + 8 * i][tx] = W[(size_t)(k0 + ty + 8 * i) * N + n0 + tx];
    __syncthreads();
#pragma unroll
    for (int i = 0; i < 4; ++i) {
        int r = ty + 8 * i;
        WT[(size_t)(n0 + r) * K + k0 + tx] = bf16_rne(tile[tx][r]);
    }
}

// ---------------------------------------------------------------------------
// bf16 MFMA GEMM (m97 structure): C[M,N] = A[M,K] @ B[K,N], fp32 accumulate.
// A row-major bf16; B given TRANSPOSED (N x K) bf16. OUT_BF16 selects C dtype.
// ---------------------------------------------------------------------------
template <bool OUT_BF16>
__global__ __launch_bounds__(256) void gemm_bf16(const u16* __restrict__ A,
                                                 const u16* __restrict__ BT,
                                                 void* __restrict__ Cv,
                                                 int M, int N, int K) {
    __shared__ u16 sm[2 * 128 * 32] __attribute__((aligned(16)));
    u16* sA = sm;          // [128][32]
    u16* sB = sm + 4096;   // [128][32]

    const int t    = threadIdx.x;
    const int w    = t >> 6;
    const int lane = t & 63;
    const int m0   = blockIdx.y * 128;
    const int n0   = blockIdx.x * 128;
    const int wr   = (w >> 1) * 64;
    const int wc   = (w & 1) * 64;

    f32x4 acc[4][4];
#pragma unroll
    for (int i = 0; i < 4; ++i)
#pragma unroll
        for (int j = 0; j < 4; ++j) acc[i][j] = (f32x4)0.f;

    const int srow = lane >> 2;
    const size_t aOff = (size_t)(m0 + 32 * w + srow) * K + (size_t)(lane & 3) * 8;
    const size_t bOff = (size_t)(n0 + 32 * w + srow) * K + (size_t)(lane & 3) * 8;
    const size_t rowStep = (size_t)16 * K;
    u16* const ldsA = sA + 1024 * w;
    u16* const ldsB = sB + 1024 * w;

    const int fr = lane & 15;
    const int fq = (lane >> 4) * 8;

    for (int k0 = 0; k0 < K; k0 += 32) {
#pragma unroll
        for (int i = 0; i < 2; ++i) {
            glds16(A  + aOff + k0 + i * rowStep, ldsA + 512 * i);
            glds16(BT + bOff + k0 + i * rowStep, ldsB + 512 * i);
        }
        __syncthreads();

        short8 af[4], bf[4];
#pragma unroll
        for (int mt = 0; mt < 4; ++mt)
            af[mt] = *(const short8*)&sA[(wr + mt * 16 + fr) * 32 + fq];
#pragma unroll
        for (int nt = 0; nt < 4; ++nt)
            bf[nt] = *(const short8*)&sB[(wc + nt * 16 + fr) * 32 + fq];
#pragma unroll
        for (int mt = 0; mt < 4; ++mt)
#pragma unroll
            for (int nt = 0; nt < 4; ++nt)
                acc[mt][nt] = __builtin_amdgcn_mfma_f32_16x16x32_bf16(af[mt], bf[nt], acc[mt][nt], 0, 0, 0);
        __syncthreads();
    }

    const int col = lane & 15;
    const int rq  = (lane >> 4) * 4;
#pragma unroll
    for (int mt = 0; mt < 4; ++mt)
#pragma unroll
        for (int nt = 0; nt < 4; ++nt)
#pragma unroll
            for (int i = 0; i < 4; ++i) {
                size_t idx = (size_t)(m0 + wr + mt * 16 + rq + i) * N + n0 + wc + nt * 16 + col;
                if (OUT_BF16) ((u16*)Cv)[idx] = bf16_rne(acc[mt][nt][i]);
                else          ((float*)Cv)[idx] = acc[mt][nt][i];
            }
}

// ---------------------------------------------------------------------------
// RoPE in place on bf16: x is (S, nh*128).
// ---------------------------------------------------------------------------
__global__ void rope_bf16(u16* __restrict__ x, const float* __restrict__ cosT,
                          const float* __restrict__ sinT, int nh) {
    int idx = blockIdx.x * blockDim.x + threadIdx.x;
    int total = S_LEN * nh * 64;
    if (idx >= total) return;
    int d = idx & 63;
    int h = (idx >> 6) % nh;
    int s = idx / (nh * 64);
    float c  = cosT[s * HD_ + d];
    float sn = sinT[s * HD_ + d];
    u16* p = x + (size_t)s * nh * HD_ + h * HD_ + d;
    float x1 = bf16_to_f(p[0]);
    float x2 = bf16_to_f(p[64]);
    p[0]  = bf16_rne(x1 * c - x2 * sn);
    p[64] = bf16_rne(x2 * c + x1 * sn);
}

// ---------------------------------------------------------------------------
// MFMA flash attention, causal GQA, bf16 in / bf16 out (fp32 accum+softmax).
// Block = (64 q-rows, 1 head); 4 waves, wave w owns q stripe [16w,16w+16).
// LDS: sQ[64][136] | union{ sK[64][136], sVt[128][72] } | sP 4x[16][72]
// ---------------------------------------------------------------------------
#define QSTR 136
#define PSTR 72
__global__ __launch_bounds__(256) void attn_mfma(const u16* __restrict__ Q,
                                                 const u16* __restrict__ K,
                                                 const u16* __restrict__ V,
                                                 u16* __restrict__ O) {
    __shared__ u16 smem[22528] __attribute__((aligned(16)));
    u16* sQ  = smem;             // 64*136 = 8704
    u16* sK  = smem + 8704;      // 64*136
    u16* sVt = smem + 8704;      // 128*72 = 9216 (union with sK)
    u16* sP  = smem + 17920;     // 4 * 16*72

    const int qt   = gridDim.x - 1 - blockIdx.x;  // heavy tiles first
    const int h    = blockIdx.y;
    const int kvh  = h >> 2;
    const int q0   = qt * 64;
    const int t    = threadIdx.x;
    const int w    = t >> 6;
    const int lane = t & 63;
    const int fr   = lane & 15;
    const int quad = lane >> 4;
    const float scale = 0.08838834764831845f;  // 1/sqrt(128)

    // ---- stage Q tile (once) ----
    {
        const int chunk = t & 15;
        const int row4  = t >> 4;  // 0..15
#pragma unroll
        for (int p = 0; p < 4; ++p) {
            int row = row4 + p * 16;
            uint4 xv = *(const uint4*)&Q[(size_t)(q0 + row) * DQ + h * HD_ + chunk * 8];
            *(uint4*)&sQ[row * QSTR + chunk * 8] = xv;
        }
    }
    __syncthreads();

    // Q fragments are kt-invariant: hold in registers
    short8 aq[4];
#pragma unroll
    for (int ks = 0; ks < 4; ++ks)
        aq[ks] = *(const short8*)&sQ[(16 * w + fr) * QSTR + ks * 32 + quad * 8];

    float mrow[4], lrow[4];
    f32x4 oacc[8];
#pragma unroll
    for (int i = 0; i < 4; ++i) { mrow[i] = -INFINITY; lrow[i] = 0.f; }
#pragma unroll
    for (int n8 = 0; n8 < 8; ++n8) oacc[n8] = (f32x4)0.f;

    u16* const sPw = sP + w * (16 * PSTR);

    for (int kt = 0; kt <= qt; ++kt) {
        const int k0 = kt * 64;
        __syncthreads();  // prev PV done with sVt before sK overwrite

        // ---- stage K tile [64][136] ----
        {
            const int chunk = t & 15;
            const int row4  = t >> 4;
#pragma unroll
            for (int p = 0; p < 4; ++p) {
                int row = row4 + p * 16;
                uint4 xv = *(const uint4*)&K[(size_t)(k0 + row) * DKV + kvh * HD_ + chunk * 8];
                *(uint4*)&sK[row * QSTR + chunk * 8] = xv;
            }
        }
        __syncthreads();

        // ---- S = Q K^T (stripe: 16 q x 64 keys) ----
        f32x4 sacc[4];
#pragma unroll
        for (int nt = 0; nt < 4; ++nt) sacc[nt] = (f32x4)0.f;
#pragma unroll
        for (int ks = 0; ks < 4; ++ks) {
#pragma unroll
            for (int nt = 0; nt < 4; ++nt) {
                short8 bk = *(const short8*)&sK[(nt * 16 + fr) * QSTR + ks * 32 + quad * 8];
                sacc[nt] = __builtin_amdgcn_mfma_f32_16x16x32_bf16(aq[ks], bk, sacc[nt], 0, 0, 0);
            }
        }

        // ---- mask + scale + row max ----
        float rmax[4];
#pragma unroll
        for (int i = 0; i < 4; ++i) rmax[i] = -INFINITY;
#pragma unroll
        for (int nt = 0; nt < 4; ++nt) {
            int key = k0 + nt * 16 + fr;
#pragma unroll
            for (int i = 0; i < 4; ++i) {
                int qg = q0 + 16 * w + quad * 4 + i;
                float s = sacc[nt][i] * scale;
                s = (key > qg) ? -INFINITY : s;
                sacc[nt][i] = s;
                rmax[i] = fmaxf(rmax[i], s);
            }
        }
#pragma unroll
        for (int i = 0; i < 4; ++i) {
            rmax[i] = fmaxf(rmax[i], __shfl_xor(rmax[i], 1));
            rmax[i] = fmaxf(rmax[i], __shfl_xor(rmax[i], 2));
            rmax[i] = fmaxf(rmax[i], __shfl_xor(rmax[i], 4));
            rmax[i] = fmaxf(rmax[i], __shfl_xor(rmax[i], 8));
        }
        float alpha[4];
#pragma unroll
        for (int i = 0; i < 4; ++i) {
            float mnew = fmaxf(mrow[i], rmax[i]);
            alpha[i] = __expf(mrow[i] - mnew);   // exp(-inf)=0 on first tile
            mrow[i] = mnew;
        }

        // ---- P = exp(S - m), row sums, write P (bf16, C->A layout round trip) ----
        float rsum[4] = {0.f, 0.f, 0.f, 0.f};
#pragma unroll
        for (int nt = 0; nt < 4; ++nt)
#pragma unroll
            for (int i = 0; i < 4; ++i) {
                float p = __expf(sacc[nt][i] - mrow[i]);
                rsum[i] += p;
                sPw[(quad * 4 + i) * PSTR + nt * 16 + fr] = bf16_rne(p);
            }
#pragma unroll
        for (int i = 0; i < 4; ++i) {
            rsum[i] += __shfl_xor(rsum[i], 1);
            rsum[i] += __shfl_xor(rsum[i], 2);
            rsum[i] += __shfl_xor(rsum[i], 4);
            rsum[i] += __shfl_xor(rsum[i], 8);
            lrow[i] = lrow[i] * alpha[i] + rsum[i];
        }
#pragma unroll
        for (int n8 = 0; n8 < 8; ++n8)
#pragma unroll
            for (int i = 0; i < 4; ++i) oacc[n8][i] *= alpha[i];

        __syncthreads();  // all waves done reading sK

        // ---- stage V^T [128 d][72-padded keys]; lane=key -> conflict-free writes
        {
            const int key = t & 63;
            const int c0  = t >> 6;   // == wave id
#pragma unroll
            for (int p = 0; p < 4; ++p) {
                int d0 = (c0 * 4 + p) * 8;
                uint4 xv = *(const uint4*)&V[(size_t)(k0 + key) * DKV + kvh * HD_ + d0];
                const u16* xp = (const u16*)&xv;
#pragma unroll
                for (int j = 0; j < 8; ++j) sVt[(d0 + j) * PSTR + key] = xp[j];
            }
        }
        __syncthreads();

        // ---- O += P V ----
#pragma unroll
        for (int ks2 = 0; ks2 < 2; ++ks2) {
            short8 ap = *(const short8*)&sPw[fr * PSTR + ks2 * 32 + quad * 8];
#pragma unroll
            for (int n8 = 0; n8 < 8; ++n8) {
                short8 bv = *(const short8*)&sVt[(n8 * 16 + fr) * PSTR + ks2 * 32 + quad * 8];
                oacc[n8] = __builtin_amdgcn_mfma_f32_16x16x32_bf16(ap, bv, oacc[n8], 0, 0, 0);
            }
        }
    }

    // ---- epilogue: normalize, store bf16 ----
#pragma unroll
    for (int i = 0; i < 4; ++i) {
        float inv = 1.f / lrow[i];
        size_t base = (size_t)(q0 + 16 * w + quad * 4 + i) * DQ + h * HD_;
#pragma unroll
        for (int n8 = 0; n8 < 8; ++n8)
            O[base + n8 * 16 + fr] = bf16_rne(oacc[n8][i] * inv);
    }
}

// ---------------------------------------------------------------------------
extern "C" void kernel_launch(void* const* d_in, const int* in_sizes, int n_in,
                              void* d_out, int out_size, void* d_ws, size_t ws_size,
                              hipStream_t stream) {
    const float* X    = (const float*)d_in[0];
    const float* cosT = (const float*)d_in[1];
    const float* sinT = (const float*)d_in[2];
    const float* wq   = (const float*)d_in[3];
    const float* wk   = (const float*)d_in[4];
    const float* wv   = (const float*)d_in[5];
    const float* wo   = (const float*)d_in[6];
    float* out = (float*)d_out;

    const size_t SDQ  = (size_t)S_LEN * DQ;    // 8.4M
    const size_t SDKV = (size_t)S_LEN * DKV;   // 2.1M
    const size_t W44  = (size_t)HDIM * DQ;     // 16.8M
    const size_t W41  = (size_t)HDIM * DKV;    // 4.2M

    // ws layout (u16 elements), ~109 MB total
    u16* Xb  = (u16*)d_ws;
    u16* qb  = Xb + SDQ;
    u16* kb  = qb + SDQ;
    u16* vb  = kb + SDKV;
    u16* aob = vb + SDKV;
    u16* wqT = aob + SDQ;    // reused for woT after projections
    u16* wkT = wqT + W44;
    u16* wvT = wkT + W41;

    dim3 blk(256);

    // convert inputs to bf16
    cvt_bf16<<<SDQ / 2048, blk, 0, stream>>>(X, Xb, (int)SDQ);
    cvtT<<<dim3(DQ / 32, HDIM / 32), blk, 0, stream>>>(wq, wqT, HDIM, DQ);
    cvtT<<<dim3(DKV / 32, HDIM / 32), blk, 0, stream>>>(wk, wkT, HDIM, DKV);
    cvtT<<<dim3(DKV / 32, HDIM / 32), blk, 0, stream>>>(wv, wvT, HDIM, DKV);

    // projections (bf16 out)
    gemm_bf16<true><<<dim3(DQ / 128, S_LEN / 128), blk, 0, stream>>>(Xb, wqT, qb, S_LEN, DQ, HDIM);
    gemm_bf16<true><<<dim3(DKV / 128, S_LEN / 128), blk, 0, stream>>>(Xb, wkT, kb, S_LEN, DKV, HDIM);
    gemm_bf16<true><<<dim3(DKV / 128, S_LEN / 128), blk, 0, stream>>>(Xb, wvT, vb, S_LEN, DKV, HDIM);

    // rope q, k (in place, bf16)
    rope_bf16<<<(S_LEN * NQ_H * 64) / 256, blk, 0, stream>>>(qb, cosT, sinT, NQ_H);
    rope_bf16<<<(S_LEN * NKV_H * 64) / 256, blk, 0, stream>>>(kb, cosT, sinT, NKV_H);

    // attention (bf16 out)
    attn_mfma<<<dim3(S_LEN / 64, NQ_H), blk, 0, stream>>>(qb, kb, vb, aob);

    // output projection (fp32 out). wo: (DQ x HDIM) -> woT (HDIM x DQ) in wqT slot
    cvtT<<<dim3(HDIM / 32, DQ / 32), blk, 0, stream>>>(wo, wqT, DQ, HDIM);
    gemm_bf16<false><<<dim3(HDIM / 128, S_LEN / 128), blk, 0, stream>>>(aob, wqT, out, S_LEN, HDIM, DQ);
}

// Round 4
// 706.658 us; speedup vs baseline: 7.2703x; 1.1449x over previous
//
#include <hip/hip_runtime.h>
#include <hip/hip_bf16.h>
#include <math.h>

// Problem constants (B=1)
#define S_LEN 2048
#define HDIM  4096
#define NQ_H  32
#define NKV_H 8
#define HD_   128
#define DQ (NQ_H*HD_)   // 4096
#define DKV (NKV_H*HD_) // 1024
#define NFUSE (DQ + 2*DKV)  // 6144

typedef unsigned short u16;
typedef unsigned int   u32;
typedef __attribute__((ext_vector_type(8))) short short8;   // 8 bf16 = 4 VGPRs
typedef __attribute__((ext_vector_type(4))) float f32x4;

__device__ __forceinline__ u16 bf16_rne(float x) {
    u32 u = __float_as_uint(x);
    u = (u + 0x7FFFu + ((u >> 16) & 1u)) >> 16;
    return (u16)u;
}
__device__ __forceinline__ float bf16_to_f(u16 h) {
    return __uint_as_float(((u32)h) << 16);
}
__device__ __forceinline__ void glds16(const u16* g, u16* l) {
    __builtin_amdgcn_global_load_lds(
        (const __attribute__((address_space(1))) u32*)g,
        (__attribute__((address_space(3))) u32*)l,
        16, 0, 0);
}

// ---------------------------------------------------------------------------
// fp32 -> bf16 row-major convert. n % 2048 == 0.
// ---------------------------------------------------------------------------
__global__ __launch_bounds__(256) void cvt_bf16(const float* __restrict__ in,
                                                u16* __restrict__ out, int n) {
    int i = (blockIdx.x * 256 + threadIdx.x) * 8;
    if (i >= n) return;
    float4 a = *(const float4*)&in[i];
    float4 b = *(const float4*)&in[i + 4];
    u16 h[8];
    h[0] = bf16_rne(a.x); h[1] = bf16_rne(a.y); h[2] = bf16_rne(a.z); h[3] = bf16_rne(a.w);
    h[4] = bf16_rne(b.x); h[5] = bf16_rne(b.y); h[6] = bf16_rne(b.z); h[7] = bf16_rne(b.w);
    *(uint4*)&out[i] = *(uint4*)h;
}

// ---------------------------------------------------------------------------
// Fused weight transpose+convert: [wq|wk|wv] columns -> WT (6144 x 4096) bf16.
// ---------------------------------------------------------------------------
__global__ __launch_bounds__(256) void cvtT_qkv(const float* __restrict__ wq,
                                                const float* __restrict__ wk,
                                                const float* __restrict__ wv,
                                                u16* __restrict__ WT) {
    __shared__ float tile[32][33];
    const int n0g = blockIdx.x * 32;   // global output row base (0..6112)
    const int k0  = blockIdx.y * 32;
    const float* W; int Nsrc, nloc0;
    if (n0g < DQ)            { W = wq; Nsrc = DQ;  nloc0 = n0g; }
    else if (n0g < DQ + DKV) { W = wk; Nsrc = DKV; nloc0 = n0g - DQ; }
    else                     { W = wv; Nsrc = DKV; nloc0 = n0g - DQ - DKV; }
    const int tx = threadIdx.x & 31;
    const int ty = threadIdx.x >> 5;   // 0..7
#pragma unroll
    for (int i = 0; i < 4; ++i)
        tile[ty + 8 * i][tx] = W[(size_t)(k0 + ty + 8 * i) * Nsrc + nloc0 + tx];
    __syncthreads();
#pragma unroll
    for (int i = 0; i < 4; ++i) {
        int r = ty + 8 * i;
        WT[(size_t)(n0g + r) * HDIM + k0 + tx] = bf16_rne(tile[tx][r]);
    }
}

// ---------------------------------------------------------------------------
// Single-source transpose+convert: W (K x N fp32) -> W^T bf16 (N x K).
// ---------------------------------------------------------------------------
__global__ __launch_bounds__(256) void cvtT(const float* __restrict__ W,
                                            u16* __restrict__ WT, int K, int N) {
    __shared__ float tile[32][33];
    const int n0 = blockIdx.x * 32;
    const int k0 = blockIdx.y * 32;
    const int tx = threadIdx.x & 31;
    const int ty = threadIdx.x >> 5;
#pragma unroll
    for (int i = 0; i < 4; ++i)
        tile[ty + 8 * i][tx] = W[(size_t)(k0 + ty + 8 * i) * N + n0 + tx];
    __syncthreads();
#pragma unroll
    for (int i = 0; i < 4; ++i) {
        int r = ty + 8 * i;
        WT[(size_t)(n0 + r) * K + k0 + tx] = bf16_rne(tile[tx][r]);
    }
}

// ---------------------------------------------------------------------------
// Fused QKV GEMM: A (2048 x 4096 bf16) @ [wq|wk|wv] via WT (6144 x 4096 bf16).
// Outputs split to qb / kb / vb (bf16). m97 structure.
// ---------------------------------------------------------------------------
__global__ __launch_bounds__(256) void gemm_qkv(const u16* __restrict__ A,
                                                const u16* __restrict__ BT,
                                                u16* __restrict__ qb,
                                                u16* __restrict__ kb,
                                                u16* __restrict__ vb) {
    const int K = HDIM, M = S_LEN;
    (void)M;
    __shared__ u16 sm[2 * 128 * 32] __attribute__((aligned(16)));
    u16* sA = sm;
    u16* sB = sm + 4096;

    const int t    = threadIdx.x;
    const int w    = t >> 6;
    const int lane = t & 63;
    const int m0   = blockIdx.y * 128;
    const int n0   = blockIdx.x * 128;
    const int wr   = (w >> 1) * 64;
    const int wc   = (w & 1) * 64;

    f32x4 acc[4][4];
#pragma unroll
    for (int i = 0; i < 4; ++i)
#pragma unroll
        for (int j = 0; j < 4; ++j) acc[i][j] = (f32x4)0.f;

    const int srow = lane >> 2;
    const size_t aOff = (size_t)(m0 + 32 * w + srow) * K + (size_t)(lane & 3) * 8;
    const size_t bOff = (size_t)(n0 + 32 * w + srow) * K + (size_t)(lane & 3) * 8;
    const size_t rowStep = (size_t)16 * K;
    u16* const ldsA = sA + 1024 * w;
    u16* const ldsB = sB + 1024 * w;

    const int fr = lane & 15;
    const int fq = (lane >> 4) * 8;

    for (int k0 = 0; k0 < K; k0 += 32) {
#pragma unroll
        for (int i = 0; i < 2; ++i) {
            glds16(A  + aOff + k0 + i * rowStep, ldsA + 512 * i);
            glds16(BT + bOff + k0 + i * rowStep, ldsB + 512 * i);
        }
        __syncthreads();
        short8 af[4], bf[4];
#pragma unroll
        for (int mt = 0; mt < 4; ++mt)
            af[mt] = *(const short8*)&sA[(wr + mt * 16 + fr) * 32 + fq];
#pragma unroll
        for (int nt = 0; nt < 4; ++nt)
            bf[nt] = *(const short8*)&sB[(wc + nt * 16 + fr) * 32 + fq];
#pragma unroll
        for (int mt = 0; mt < 4; ++mt)
#pragma unroll
            for (int nt = 0; nt < 4; ++nt)
                acc[mt][nt] = __builtin_amdgcn_mfma_f32_16x16x32_bf16(af[mt], bf[nt], acc[mt][nt], 0, 0, 0);
        __syncthreads();
    }

    // region select (block n-span = 128, regions 128-aligned)
    u16* dst; int stride, nbase;
    if (n0 < DQ)            { dst = qb; stride = DQ;  nbase = n0; }
    else if (n0 < DQ + DKV) { dst = kb; stride = DKV; nbase = n0 - DQ; }
    else                    { dst = vb; stride = DKV; nbase = n0 - DQ - DKV; }

    const int col = lane & 15;
    const int rq  = (lane >> 4) * 4;
#pragma unroll
    for (int mt = 0; mt < 4; ++mt)
#pragma unroll
        for (int nt = 0; nt < 4; ++nt)
#pragma unroll
            for (int i = 0; i < 4; ++i)
                dst[(size_t)(m0 + wr + mt * 16 + rq + i) * stride + nbase + wc + nt * 16 + col] =
                    bf16_rne(acc[mt][nt][i]);
}

// ---------------------------------------------------------------------------
// O-projection GEMM: ao (bf16) @ woT -> fp32 out. m97 structure.
// ---------------------------------------------------------------------------
__global__ __launch_bounds__(256) void gemm_out(const u16* __restrict__ A,
                                                const u16* __restrict__ BT,
                                                float* __restrict__ C,
                                                int M, int N, int K) {
    __shared__ u16 sm[2 * 128 * 32] __attribute__((aligned(16)));
    u16* sA = sm;
    u16* sB = sm + 4096;

    const int t    = threadIdx.x;
    const int w    = t >> 6;
    const int lane = t & 63;
    const int m0   = blockIdx.y * 128;
    const int n0   = blockIdx.x * 128;
    const int wr   = (w >> 1) * 64;
    const int wc   = (w & 1) * 64;

    f32x4 acc[4][4];
#pragma unroll
    for (int i = 0; i < 4; ++i)
#pragma unroll
        for (int j = 0; j < 4; ++j) acc[i][j] = (f32x4)0.f;

    const int srow = lane >> 2;
    const size_t aOff = (size_t)(m0 + 32 * w + srow) * K + (size_t)(lane & 3) * 8;
    const size_t bOff = (size_t)(n0 + 32 * w + srow) * K + (size_t)(lane & 3) * 8;
    const size_t rowStep = (size_t)16 * K;
    u16* const ldsA = sA + 1024 * w;
    u16* const ldsB = sB + 1024 * w;

    const int fr = lane & 15;
    const int fq = (lane >> 4) * 8;

    for (int k0 = 0; k0 < K; k0 += 32) {
#pragma unroll
        for (int i = 0; i < 2; ++i) {
            glds16(A  + aOff + k0 + i * rowStep, ldsA + 512 * i);
            glds16(BT + bOff + k0 + i * rowStep, ldsB + 512 * i);
        }
        __syncthreads();
        short8 af[4], bf[4];
#pragma unroll
        for (int mt = 0; mt < 4; ++mt)
            af[mt] = *(const short8*)&sA[(wr + mt * 16 + fr) * 32 + fq];
#pragma unroll
        for (int nt = 0; nt < 4; ++nt)
            bf[nt] = *(const short8*)&sB[(wc + nt * 16 + fr) * 32 + fq];
#pragma unroll
        for (int mt = 0; mt < 4; ++mt)
#pragma unroll
            for (int nt = 0; nt < 4; ++nt)
                acc[mt][nt] = __builtin_amdgcn_mfma_f32_16x16x32_bf16(af[mt], bf[nt], acc[mt][nt], 0, 0, 0);
        __syncthreads();
    }

    const int col = lane & 15;
    const int rq  = (lane >> 4) * 4;
#pragma unroll
    for (int mt = 0; mt < 4; ++mt)
#pragma unroll
        for (int nt = 0; nt < 4; ++nt)
#pragma unroll
            for (int i = 0; i < 4; ++i)
                C[(size_t)(m0 + wr + mt * 16 + rq + i) * N + n0 + wc + nt * 16 + col] = acc[mt][nt][i];
}

// ---------------------------------------------------------------------------
// Fused RoPE (q then k regions), bf16 in-place, 4 d-elements per thread.
// ---------------------------------------------------------------------------
__global__ __launch_bounds__(256) void rope2(u16* __restrict__ q, u16* __restrict__ k,
                                             const float* __restrict__ cosT,
                                             const float* __restrict__ sinT) {
    int idx = blockIdx.x * 256 + threadIdx.x;     // S * 40 * 16
    int d4   = (idx & 15) * 4;                    // 0..60
    int rest = idx >> 4;
    int head = rest % (NQ_H + NKV_H);
    int s    = rest / (NQ_H + NKV_H);
    u16* base = (head < NQ_H)
        ? q + ((size_t)s * NQ_H + head) * HD_
        : k + ((size_t)s * NKV_H + (head - NQ_H)) * HD_;
    float4 c  = *(const float4*)&cosT[s * HD_ + d4];
    float4 sn = *(const float4*)&sinT[s * HD_ + d4];
    u16 lo[4], hi[4];
    *(uint2*)lo = *(uint2*)&base[d4];
    *(uint2*)hi = *(uint2*)&base[d4 + 64];
    float cs[4] = {c.x, c.y, c.z, c.w};
    float ss[4] = {sn.x, sn.y, sn.z, sn.w};
    u16 nlo[4], nhi[4];
#pragma unroll
    for (int j = 0; j < 4; ++j) {
        float x1 = bf16_to_f(lo[j]);
        float x2 = bf16_to_f(hi[j]);
        nlo[j] = bf16_rne(x1 * cs[j] - x2 * ss[j]);
        nhi[j] = bf16_rne(x2 * cs[j] + x1 * ss[j]);
    }
    *(uint2*)&base[d4]      = *(uint2*)nlo;
    *(uint2*)&base[d4 + 64] = *(uint2*)nhi;
}

// ---------------------------------------------------------------------------
// V (S x 1024 bf16) -> Vt[kvh][d][s] (bf16): per-head transposed.
// ---------------------------------------------------------------------------
__global__ __launch_bounds__(256) void transpose_v(const u16* __restrict__ V,
                                                   u16* __restrict__ Vt) {
    __shared__ u16 tile[64][72];
    const int s0  = blockIdx.x * 64;
    const int kvh = blockIdx.y >> 1;
    const int d0  = (blockIdx.y & 1) * 64;
    const int t = threadIdx.x;
    const int chunk = t & 7;       // 8 x 16B per 64-wide row
    const int row   = t >> 3;      // 0..31
#pragma unroll
    for (int p = 0; p < 2; ++p) {
        int s = row + 32 * p;
        uint4 x = *(const uint4*)&V[(size_t)(s0 + s) * DKV + kvh * HD_ + d0 + chunk * 8];
        *(uint4*)&tile[s][chunk * 8] = x;
    }
    __syncthreads();
#pragma unroll
    for (int p = 0; p < 2; ++p) {
        int d = row + 32 * p;
        u16 tmp[8];
#pragma unroll
        for (int j = 0; j < 8; ++j) tmp[j] = tile[chunk * 8 + j][d];
        *(uint4*)&Vt[(size_t)(kvh * HD_ + d0 + d) * S_LEN + s0 + chunk * 8] = *(uint4*)tmp;
    }
}

// ---------------------------------------------------------------------------
// MFMA flash attention, causal GQA, fixed-base softmax (exact after o/l).
// Block = (64 q-rows, head); 4 waves; 2 barriers/iter; V pre-transposed.
// LDS: sK[64][136] | sVt[128][72] (union sQ) | sP 4x[16][76]
// ---------------------------------------------------------------------------
#define KSTR 136
#define VSTR 72
#define PSTR 76
__global__ __launch_bounds__(256) void attn_mfma(const u16* __restrict__ Q,
                                                 const u16* __restrict__ K,
                                                 const u16* __restrict__ Vt,
                                                 u16* __restrict__ O) {
    __shared__ u16 smem[64 * KSTR + 128 * VSTR + 4 * 16 * PSTR] __attribute__((aligned(16)));
    u16* sK  = smem;                       // 64*136 = 8704
    u16* sVt = smem + 64 * KSTR;           // 128*72 = 9216
    u16* sQ  = sVt;                        // union (sQ only live pre-loop)
    u16* sP  = smem + 64 * KSTR + 128 * VSTR;

    const int qt   = gridDim.x - 1 - blockIdx.x;  // heavy tiles first
    const int h    = blockIdx.y;
    const int kvh  = h >> 2;
    const int q0   = qt * 64;
    const int t    = threadIdx.x;
    const int w    = t >> 6;
    const int lane = t & 63;
    const int fr   = lane & 15;
    const int quad = lane >> 4;

    // p = exp(s*scale - 8) = exp2(s*K1 - K2)
    const float K1 = 0.12751744154f;   // (1/sqrt(128)) * log2(e)
    const float K2 = 11.5415603267f;   // 8 * log2(e)

    // ---- stage Q tile once ----
    {
        const int chunk = t & 15;
        const int row4  = t >> 4;
#pragma unroll
        for (int p = 0; p < 4; ++p) {
            int row = row4 + p * 16;
            uint4 xv = *(const uint4*)&Q[(size_t)(q0 + row) * DQ + h * HD_ + chunk * 8];
            *(uint4*)&sQ[row * KSTR + chunk * 8] = xv;
        }
    }
    __syncthreads();

    short8 aq[4];
#pragma unroll
    for (int ks = 0; ks < 4; ++ks)
        aq[ks] = *(const short8*)&sQ[(16 * w + fr) * KSTR + ks * 32 + quad * 8];

    float lrow[4] = {0.f, 0.f, 0.f, 0.f};
    f32x4 oacc[8];
#pragma unroll
    for (int n8 = 0; n8 < 8; ++n8) oacc[n8] = (f32x4)0.f;

    u16* const sPw = sP + w * (16 * PSTR);

    for (int kt = 0; kt <= qt; ++kt) {
        const int k0 = kt * 64;
        __syncthreads();  // aq reads done (iter 0) / prev PV reads done

        // ---- stage K [64][KSTR] ----
        {
            const int chunk = t & 15;
            const int row4  = t >> 4;
#pragma unroll
            for (int p = 0; p < 4; ++p) {
                int row = row4 + p * 16;
                uint4 xv = *(const uint4*)&K[(size_t)(k0 + row) * DKV + kvh * HD_ + chunk * 8];
                *(uint4*)&sK[row * KSTR + chunk * 8] = xv;
            }
        }
        // ---- stage V^T [128][VSTR] (rows = d, 64 keys each) ----
        {
            const int chunk = t & 7;
            const int drow  = t >> 3;   // 0..31
#pragma unroll
            for (int p = 0; p < 4; ++p) {
                int d = drow + 32 * p;
                uint4 xv = *(const uint4*)&Vt[(size_t)(kvh * HD_ + d) * S_LEN + k0 + chunk * 8];
                *(uint4*)&sVt[d * VSTR + chunk * 8] = xv;
            }
        }
        __syncthreads();

        // ---- S = Q K^T ----
        f32x4 sacc[4];
#pragma unroll
        for (int nt = 0; nt < 4; ++nt) sacc[nt] = (f32x4)0.f;
#pragma unroll
        for (int ks = 0; ks < 4; ++ks)
#pragma unroll
            for (int nt = 0; nt < 4; ++nt) {
                short8 bk = *(const short8*)&sK[(nt * 16 + fr) * KSTR + ks * 32 + quad * 8];
                sacc[nt] = __builtin_amdgcn_mfma_f32_16x16x32_bf16(aq[ks], bk, sacc[nt], 0, 0, 0);
            }

        // ---- causal mask only on diagonal tile ----
        if (kt == qt) {
#pragma unroll
            for (int nt = 0; nt < 4; ++nt) {
                int key = nt * 16 + fr;
#pragma unroll
                for (int i = 0; i < 4; ++i) {
                    int qg = 16 * w + quad * 4 + i;
                    if (key > qg) sacc[nt][i] = -INFINITY;
                }
            }
        }

        // ---- P = exp2(S*K1 - K2); accumulate l; write P (C->A round trip) ----
#pragma unroll
        for (int nt = 0; nt < 4; ++nt)
#pragma unroll
            for (int i = 0; i < 4; ++i) {
                float p = __builtin_amdgcn_exp2f(fmaf(sacc[nt][i], K1, -K2));
                lrow[i] += p;
                sPw[(quad * 4 + i) * PSTR + nt * 16 + fr] = bf16_rne(p);
            }

        // ---- O += P V ----
#pragma unroll
        for (int ks2 = 0; ks2 < 2; ++ks2) {
            short8 ap = *(const short8*)&sPw[fr * PSTR + ks2 * 32 + quad * 8];
#pragma unroll
            for (int n8 = 0; n8 < 8; ++n8) {
                short8 bv = *(const short8*)&sVt[(n8 * 16 + fr) * VSTR + ks2 * 32 + quad * 8];
                oacc[n8] = __builtin_amdgcn_mfma_f32_16x16x32_bf16(ap, bv, oacc[n8], 0, 0, 0);
            }
        }
    }

    // ---- epilogue: reduce l across fr, normalize, store ----
#pragma unroll
    for (int i = 0; i < 4; ++i) {
        lrow[i] += __shfl_xor(lrow[i], 1);
        lrow[i] += __shfl_xor(lrow[i], 2);
        lrow[i] += __shfl_xor(lrow[i], 4);
        lrow[i] += __shfl_xor(lrow[i], 8);
    }
#pragma unroll
    for (int i = 0; i < 4; ++i) {
        float inv = 1.f / lrow[i];
        size_t base = (size_t)(q0 + 16 * w + quad * 4 + i) * DQ + h * HD_;
#pragma unroll
        for (int n8 = 0; n8 < 8; ++n8)
            O[base + n8 * 16 + fr] = bf16_rne(oacc[n8][i] * inv);
    }
}

// ---------------------------------------------------------------------------
extern "C" void kernel_launch(void* const* d_in, const int* in_sizes, int n_in,
                              void* d_out, int out_size, void* d_ws, size_t ws_size,
                              hipStream_t stream) {
    const float* X    = (const float*)d_in[0];
    const float* cosT = (const float*)d_in[1];
    const float* sinT = (const float*)d_in[2];
    const float* wq   = (const float*)d_in[3];
    const float* wk   = (const float*)d_in[4];
    const float* wv   = (const float*)d_in[5];
    const float* wo   = (const float*)d_in[6];
    float* out = (float*)d_out;

    const size_t SDQ  = (size_t)S_LEN * DQ;    // 8.4M
    const size_t SDKV = (size_t)S_LEN * DKV;   // 2.1M
    const size_t W44  = (size_t)HDIM * DQ;     // 16.8M
    const size_t WQKV = (size_t)HDIM * NFUSE;  // 25.2M

    // ws layout (u16), ~147 MB
    u16* Xb  = (u16*)d_ws;
    u16* qb  = Xb + SDQ;
    u16* kb  = qb + SDQ;
    u16* vb  = kb + SDKV;
    u16* vtb = vb + SDKV;
    u16* aob = vtb + SDKV;
    u16* WT  = aob + SDQ;      // fused qkv weights, 6144 x 4096
    u16* woT = WT + WQKV;

    dim3 blk(256);

    // conversions (all independent of intermediates — run up front)
    cvt_bf16<<<SDQ / 2048, blk, 0, stream>>>(X, Xb, (int)SDQ);
    cvtT_qkv<<<dim3(NFUSE / 32, HDIM / 32), blk, 0, stream>>>(wq, wk, wv, WT);
    cvtT<<<dim3(HDIM / 32, DQ / 32), blk, 0, stream>>>(wo, woT, DQ, HDIM);

    // fused QKV projection
    gemm_qkv<<<dim3(NFUSE / 128, S_LEN / 128), blk, 0, stream>>>(Xb, WT, qb, kb, vb);

    // fused rope (q + k)
    rope2<<<(S_LEN * (NQ_H + NKV_H) * 16) / 256, blk, 0, stream>>>(qb, kb, cosT, sinT);

    // V pre-transpose for attention
    transpose_v<<<dim3(S_LEN / 64, NKV_H * 2), blk, 0, stream>>>(vb, vtb);

    // attention
    attn_mfma<<<dim3(S_LEN / 64, NQ_H), blk, 0, stream>>>(qb, kb, vtb, aob);

    // output projection
    gemm_out<<<dim3(HDIM / 128, S_LEN / 128), blk, 0, stream>>>(aob, woT, out, S_LEN, HDIM, DQ);
}